// Round 22
// baseline (19.726 us; speedup 1.0000x reference)
//
#include <hip/hip_runtime.h>
#include <hip/hip_fp16.h>

#define D 300
#define NS 256
#define NA 256
#define W 8
#define NCHUNK 10     // K padded to 10 chunks of 32 (320)

typedef _Float16 half8 __attribute__((ext_vector_type(8)));
typedef float f32x4 __attribute__((ext_vector_type(4)));

__device__ __forceinline__ ushort4 cvt4(float4 v) {
    ushort4 h;
    h.x = __half_as_ushort(__float2half(v.x));
    h.y = __half_as_ushort(__float2half(v.y));
    h.z = __half_as_ushort(__float2half(v.z));
    h.w = __half_as_ushort(__float2half(v.w));
    return h;
}

// ---- prep: 256 blocks (1/CU). Block rt stages 16 rows; sen blocks also
//      compute out2 for their 2 complete categories from LDS (no tail). ----
__global__ __launch_bounds__(256) void k_prep(const float* __restrict__ emb,
                                              const int* __restrict__ sen_cats,
                                              const int* __restrict__ ann_cats,
                                              const int* __restrict__ none_idx,
                                              unsigned short* __restrict__ AH,
                                              unsigned short* __restrict__ BH,
                                              float* __restrict__ rsn,
                                              float* __restrict__ ran,
                                              int* __restrict__ sflag,
                                              float* __restrict__ out2) {
    // fp16 swizzled tile: [c(10)][lane(64)][e(8)] = 10,240 B
    __shared__ _Float16 tile[NCHUNK][64][8];
    // fp32 row values for out2: [row(16)][float4 idx(80)] = 20,480 B
    __shared__ float4 val[16][80];

    int blk = blockIdx.x, t = threadIdx.x;
    bool isSen = blk < 128;
    int rt = isSen ? blk : blk - 128;
    const int* cats = isSen ? sen_cats : ann_cats;
    unsigned short* HI = isSen ? AH : BH;

    int lr = t >> 4, f0 = t & 15;          // row-in-tile, float4 phase
    int r = rt * 16 + lr;
    int cat = cats[r];
    const float4* src = reinterpret_cast<const float4*>(emb + (size_t)cat * D);

    double acc = 0.0;
#pragma unroll
    for (int j = 0; j < 5; ++j) {
        int fidx = f0 + 16 * j;            // 0..79
        int k0 = fidx * 4;
        int c = k0 >> 5, lk = (k0 & 31) >> 3, e = k0 & 7;   // e in {0,4}
        ushort4* dp = reinterpret_cast<ushort4*>(&tile[c][lk * 16 + lr][e]);
        if (fidx < 75) {
            float4 v = src[fidx];
            *dp = cvt4(v);
            if (isSen) val[lr][fidx] = v;
            acc += (double)v.x * v.x + (double)v.y * v.y +
                   (double)v.z * v.z + (double)v.w * v.w;
        } else {                           // fidx 75..79 -> zero K-pad
            ushort4 z = {0, 0, 0, 0};
            *dp = z;
        }
    }
    // norm reduce within each 16-lane row group
    for (int m = 8; m > 0; m >>= 1) acc += __shfl_xor(acc, m, 64);
    if (f0 == 0) {
        float rn = (float)(1.0 / sqrt(acc));   // norms ~17, eps unreachable
        if (isSen) {
            rsn[r] = rn;
            sflag[r] = (cat == none_idx[0]) ? 1 : 0;
        } else {
            ran[r] = rn;
        }
    }
    __syncthreads();

    // coalesced slab dump: 640 float4 = 10,240 B contiguous
    const float4* tl = reinterpret_cast<const float4*>(&tile[0][0][0]);
    float4* dst = reinterpret_cast<float4*>(HI + (size_t)rt * 5120);
    dst[t] = tl[t];
    dst[t + 256] = tl[t + 256];
    if (t < 128) dst[t + 512] = tl[t + 512];

    // out2 for the block's 2 sen categories (w-ascending fp32 adds, ref order)
    if (isSen && t < 150) {
        int c = t / 75, fidx = t - c * 75;
        float4 s = make_float4(0.f, 0.f, 0.f, 0.f);
#pragma unroll
        for (int w = 0; w < W; ++w) {
            float4 v = val[c * 8 + w][fidx];
            s.x += v.x; s.y += v.y; s.z += v.z; s.w += v.w;
        }
        reinterpret_cast<float4*>(out2 + (size_t)(rt * 2 + c) * D)[fidx] = s;
    }
}

// ---- main: single-pass fp16 MFMA, XCD-aware tile swizzle (T1) ----
__global__ __launch_bounds__(256, 1) void k_main(const unsigned short* __restrict__ AHu,
                                                 const unsigned short* __restrict__ BHu,
                                                 const float* __restrict__ rsn,
                                                 const float* __restrict__ ran,
                                                 const int* __restrict__ sflag,
                                                 float* __restrict__ out) {
    const _Float16* AH = reinterpret_cast<const _Float16*>(AHu);
    const _Float16* BH = reinterpret_cast<const _Float16*>(BHu);

    __shared__ float cosld[128][128];   // 64 KB exactly

    int tid = threadIdx.x;
    int wv = tid >> 6, lane = tid & 63;
    int wy = wv >> 1, wx = wv & 1;      // wave's 64x64 quadrant
    int lr = lane & 15;
    int lk = lane >> 4;

    // T1: HW maps wg i -> XCD (i % 8). Each XCD owns a contiguous 4x8 tile
    // rectangle: 4 A-panels + 8 B-panels = 960 KB << 4 MB L2.
    int blk = blockIdx.x;
    int xcd = blk & 7, j = blk >> 3;
    int by = (xcd >> 1) * 4 + (j >> 3);
    int bx = (xcd & 1) * 8 + (j & 7);

    int aBase[4], bBase[4];
#pragma unroll
    for (int m = 0; m < 4; ++m)
        aBase[m] = (((by * 8 + wy * 4 + m) * NCHUNK) * 64 + lane) * 8;
#pragma unroll
    for (int n = 0; n < 4; ++n)
        bBase[n] = (((bx * 8 + wx * 4 + n) * NCHUNK) * 64 + lane) * 8;

    f32x4 acc[4][4] = {};
    half8 Ah[4], Bh[4];

#pragma unroll
    for (int c = 0; c < NCHUNK; ++c) {
        int co = c * 512;
#pragma unroll
        for (int m = 0; m < 4; ++m)
            Ah[m] = *reinterpret_cast<const half8*>(AH + aBase[m] + co);
#pragma unroll
        for (int n = 0; n < 4; ++n)
            Bh[n] = *reinterpret_cast<const half8*>(BH + bBase[n] + co);
#pragma unroll
        for (int m = 0; m < 4; ++m)
#pragma unroll
            for (int n = 0; n < 4; ++n)
                acc[m][n] = __builtin_amdgcn_mfma_f32_16x16x32_f16(Ah[m], Bh[n], acc[m][n], 0, 0, 0);
    }

    // epilogue: cosine scale (C/D: col=lane&15, row=(lane>>4)*4+reg) -> LDS
#pragma unroll
    for (int m = 0; m < 4; ++m) {
        int rbase = wy * 64 + m * 16 + lk * 4;
#pragma unroll
        for (int r = 0; r < 4; ++r) {
            int grow = by * 128 + rbase + r;
            float rsv = rsn[grow];
            float fm = sflag[grow] ? 0.f : 1.f;
            float rf = rsv * fm;
#pragma unroll
            for (int n = 0; n < 4; ++n) {
                int lc = wx * 64 + n * 16 + lr;
                float rav = ran[bx * 128 + lc];
                cosld[rbase + r][lc] = acc[m][n][r] * rf * rav;
            }
        }
    }
    __syncthreads();

    // order-dependent fold: one (s,a) pair per thread, w-major order
    int pi = tid >> 4, pj = tid & 15;
    float cur = 0.f;
#pragma unroll
    for (int w = 0; w < W; ++w) {
        const float* rowp = &cosld[pi * 8 + w][pj * 8];
#pragma unroll
        for (int v = 0; v < W; ++v) {
            float sv = rowp[v];
            cur = (sv >= cur || sv < 0.f) ? sv : cur;
        }
    }
    out[(by * 16 + pi) * NA + (bx * 16 + pj)] = cur;
}

extern "C" void kernel_launch(void* const* d_in, const int* in_sizes, int n_in,
                              void* d_out, int out_size, void* d_ws, size_t ws_size,
                              hipStream_t stream) {
    const float* emb = (const float*)d_in[0];
    const int* sen = (const int*)d_in[1];
    const int* ann = (const int*)d_in[2];
    const int* none = (const int*)d_in[3];
    float* out = (float*)d_out;

    char* ws = (char*)d_ws;
    unsigned short* AH = (unsigned short*)(ws + 0);          // 2048*320*2 = 1,310,720
    unsigned short* BH = (unsigned short*)(ws + 1310720);    // 1,310,720
    float* rsn = (float*)(ws + 2621440);                     // 8,192
    float* ran = (float*)(ws + 2629632);                     // 8,192
    int* sflag = (int*)(ws + 2637824);                       // 8,192

    hipLaunchKernelGGL(k_prep, dim3(256), dim3(256), 0, stream,
                       emb, sen, ann, none, AH, BH, rsn, ran, sflag,
                       out + NS * NA);
    hipLaunchKernelGGL(k_main, dim3(256), dim3(256), 0, stream,
                       AH, BH, rsn, ran, sflag, out);
}